// Round 9
// baseline (19.473 us; speedup 1.0000x reference)
//
#include <hip/hip_runtime.h>

// Shapes (fixed by the problem)
#define B_   32
#define N_   64
#define C_   256
#define H_   256
#define L_   16
#define NPAIR 4096
#define PPB   512            // pairs per block

typedef __attribute__((ext_vector_type(8))) _Float16 f16x8;
typedef __attribute__((ext_vector_type(2))) _Float16 f16x2;
typedef __attribute__((ext_vector_type(4))) float    f32x4;

static __device__ __forceinline__ unsigned short f2h_u(float f) {
    return __builtin_bit_cast(unsigned short, (_Float16)f);   // v_cvt_f16_f32 RNE
}

// KEY IDENTITY: the reference coef sum telescopes:
//   coef[p,n] = [spd[p,len-1]==n] - [spd[p,0]==n]
// so out[b,p] = sum_h W2[h] * prelu( y[b,e,h] - y[b,h0,h] ),  y = src @ W1^T.
//
// Single kernel, grid 256 = (b:32) x (pg:8 x 512 pairs), 512 threads (8 waves).
// LDS: sfl 32KB  src[b] f16 [n][c] rows 512B, 16B-granule XOR (n&7)<<4
//      yl  32KB  y[b]  f16 [n][h] rows 512B, 32B-granule XOR (n&7)<<5
//      w2l 512B  W2 f16 linear
__global__ __launch_bounds__(512, 2)
void kFused(const float* __restrict__ src,
            const float* __restrict__ W1,
            const float* __restrict__ W2,
            const float* __restrict__ prelu_a,
            const int*   __restrict__ spd,
            const int*   __restrict__ spd_len,
            float*       __restrict__ out) {
    __shared__ char sfl[32768];
    __shared__ char yl[32768];
    __shared__ char w2l[512];

    const int bid = blockIdx.x, b = bid >> 3, pg = bid & 7;
    const int tid = threadIdx.x, lane = tid & 63, w = tid >> 6;
    const int l15 = lane & 15, lg = lane >> 4;

    // issue stage-2 index loads early (latency hidden under phase Y)
    const int gp  = pg * PPB + tid;                 // this thread's pair
    const int len = spd_len[gp];
    const int n_h = spd[gp * L_];                   // h0 = spd[p,0]
    const int n_e = spd[gp * L_ + len - 1];         // e  = spd[p,len-1]

    // W2 -> LDS f16
    if (tid < 32) {
        float4 q0 = *(const float4*)(W2 + tid * 8);
        float4 q1 = *(const float4*)(W2 + tid * 8 + 4);
        unsigned pk0 = f2h_u(q0.x) | ((unsigned)f2h_u(q0.y) << 16);
        unsigned pk1 = f2h_u(q0.z) | ((unsigned)f2h_u(q0.w) << 16);
        unsigned pk2 = f2h_u(q1.x) | ((unsigned)f2h_u(q1.y) << 16);
        unsigned pk3 = f2h_u(q1.z) | ((unsigned)f2h_u(q1.w) << 16);
        int4 v; v.x = pk0; v.y = pk1; v.z = pk2; v.w = pk3;
        *(int4*)(w2l + tid * 16) = v;
    }

    // ---- stage src[b] -> LDS f16 (fully coalesced global; conflict-free LDS)
    {
        const float4* sb = (const float4*)(src + (size_t)b * (N_ * C_));
        #pragma unroll
        for (int i = 0; i < 8; ++i) {
            const int f = i * 512 + tid;            // flat float4 index
            const int n = f >> 6, c4 = f & 63;      // row n, c4-th float4
            float4 q = sb[f];
            unsigned pk0 = f2h_u(q.x) | ((unsigned)f2h_u(q.y) << 16);
            unsigned pk1 = f2h_u(q.z) | ((unsigned)f2h_u(q.w) << 16);
            int2 v; v.x = (int)pk0; v.y = (int)pk1;
            const unsigned off = (unsigned)(n * 512) +
                (((unsigned)(c4 * 8)) ^ ((unsigned)(n & 7) << 4));
            *(int2*)(sfl + off) = v;
        }
    }
    __syncthreads();

    // ---- phase Y: y[n][h] = sum_c src[n][c]*W1[h][c]; single-pass f16 W1.
    // wave w owns h-tiles {2w, 2w+1}. A=W1 (rows h), B=src (cols n).
    // D: col(l15)=n, row(lg*4+r)=h-sub -> 4 consecutive h per lane = b64 write.
    {
        f32x4 acc[2][4];
        #pragma unroll
        for (int i2 = 0; i2 < 2; ++i2)
            #pragma unroll
            for (int nt = 0; nt < 4; ++nt) acc[i2][nt] = (f32x4){0.f,0.f,0.f,0.f};

        #pragma unroll
        for (int kc = 0; kc < 8; ++kc) {
            f16x8 sa[4];
            #pragma unroll
            for (int nt = 0; nt < 4; ++nt) {
                const int n = nt * 16 + l15;
                const unsigned off = (unsigned)(n * 512) +
                    (((unsigned)(kc * 64 + lg * 16)) ^ ((unsigned)(n & 7) << 4));
                sa[nt] = *(const f16x8*)(sfl + off);
            }
            #pragma unroll
            for (int i2 = 0; i2 < 2; ++i2) {
                const int h = (w * 2 + i2) * 16 + l15;
                const float* wp = W1 + h * C_ + kc * 32 + lg * 8;
                float4 q0 = *(const float4*)wp;
                float4 q1 = *(const float4*)(wp + 4);
                f16x8 wh;
                wh[0] = (_Float16)q0.x; wh[1] = (_Float16)q0.y;
                wh[2] = (_Float16)q0.z; wh[3] = (_Float16)q0.w;
                wh[4] = (_Float16)q1.x; wh[5] = (_Float16)q1.y;
                wh[6] = (_Float16)q1.z; wh[7] = (_Float16)q1.w;
                #pragma unroll
                for (int nt = 0; nt < 4; ++nt)
                    acc[i2][nt] = __builtin_amdgcn_mfma_f32_16x16x32_f16(wh, sa[nt], acc[i2][nt], 0, 0, 0);
            }
        }

        // write y: lane holds h = ht*16+lg*4..+3 at n = nt*16+l15
        #pragma unroll
        for (int i2 = 0; i2 < 2; ++i2) {
            const int ht = w * 2 + i2;
            #pragma unroll
            for (int nt = 0; nt < 4; ++nt) {
                const int n = nt * 16 + l15;
                unsigned pk0 = f2h_u(acc[i2][nt][0]) | ((unsigned)f2h_u(acc[i2][nt][1]) << 16);
                unsigned pk1 = f2h_u(acc[i2][nt][2]) | ((unsigned)f2h_u(acc[i2][nt][3]) << 16);
                int2 v; v.x = (int)pk0; v.y = (int)pk1;
                const unsigned off = (unsigned)(n * 512) +
                    (((unsigned)(ht * 32)) ^ ((unsigned)(n & 7) << 5)) + (unsigned)(lg * 8);
                *(int2*)(yl + off) = v;
            }
        }
    }
    __syncthreads();

    // ---- stage 2: out[b,gp] = sum_h w2[h]*prelu(y[e][h]-y[h0][h]).
    // Thread owns its pair fully: no shuffles, no cross-lane reduce.
    {
        const float a = *prelu_a;
        float accP = 0.f, accN = 0.f;
        const char* re = yl + n_e * 512;
        const char* rh = yl + n_h * 512;
        const unsigned se = ((unsigned)(n_e & 7)) << 5;
        const unsigned sh = ((unsigned)(n_h & 7)) << 5;
        #pragma unroll 4
        for (int c = 0; c < 32; ++c) {
            f16x8 ye  = *(const f16x8*)(re + (((unsigned)(c * 16)) ^ se));
            f16x8 yh  = *(const f16x8*)(rh + (((unsigned)(c * 16)) ^ sh));
            f16x8 w2c = *(const f16x8*)(w2l + c * 16);
            f16x8 d = ye - yh;                        // v_pk_add_f16 (neg)
            f16x8 z = {};
            f16x8 pos = __builtin_elementwise_max(d, z);   // v_pk_max_f16
            f16x8 neg = __builtin_elementwise_min(d, z);   // v_pk_min_f16
            const int4 pi = __builtin_bit_cast(int4, pos);
            const int4 ni = __builtin_bit_cast(int4, neg);
            const int4 wi = __builtin_bit_cast(int4, w2c);
            const int pa[4] = {pi.x, pi.y, pi.z, pi.w};
            const int na[4] = {ni.x, ni.y, ni.z, ni.w};
            const int wa[4] = {wi.x, wi.y, wi.z, wi.w};
            #pragma unroll
            for (int i = 0; i < 4; ++i) {
                f16x2 p2 = __builtin_bit_cast(f16x2, pa[i]);
                f16x2 n2 = __builtin_bit_cast(f16x2, na[i]);
                f16x2 w2 = __builtin_bit_cast(f16x2, wa[i]);
#if __has_builtin(__builtin_amdgcn_fdot2)
                accP = __builtin_amdgcn_fdot2(p2, w2, accP, false);
                accN = __builtin_amdgcn_fdot2(n2, w2, accN, false);
#else
                accP += (float)p2[0]*(float)w2[0] + (float)p2[1]*(float)w2[1];
                accN += (float)n2[0]*(float)w2[0] + (float)n2[1]*(float)w2[1];
#endif
            }
        }
        out[b * NPAIR + gp] = accP + a * accN;   // prelu = max(x,0) + a*min(x,0)
    }
}

// ---------------------------------------------------------------------------
extern "C" void kernel_launch(void* const* d_in, const int* in_sizes, int n_in,
                              void* d_out, int out_size, void* d_ws, size_t ws_size,
                              hipStream_t stream) {
    const float* src     = (const float*)d_in[0];
    const float* W1      = (const float*)d_in[1];
    const float* W2      = (const float*)d_in[2];
    const float* prelu_a = (const float*)d_in[3];
    const int*   spd     = (const int*)d_in[4];
    const int*   spd_len = (const int*)d_in[5];
    float* out = (float*)d_out;

    kFused<<<256, 512, 0, stream>>>(src, W1, W2, prelu_a, spd, spd_len, out);
}